// Round 7
// baseline (278.633 us; speedup 1.0000x reference)
//
#include <hip/hip_runtime.h>
#include <hip/hip_bf16.h>
#include <math.h>

// DiT block. b=64, n=512 (8x8x8), d=128, H=4, dk=32.
// Round 7 == Round 5 with compile fix: __exp2f -> __builtin_amdgcn_exp2f
// (glibc math.h reserves __exp2f). Swapped QK^T, in-register P, 64KB LDS,
// 512-thread k_attn blocks.
// ws layout (bytes):
//   Qb  bf16 [64][4][512][32]   8 MB  (pre-scaled by log2e/sqrt(32))
//   Kb  bf16 [64][4][512][32]   8 MB
//   Vtb bf16 [64][4][32][512]   8 MB  (transposed [dk][n])
//   Ob  bf16 [64][512][128]     8 MB  (i-ordered: i = k*4+h, permute pre-applied)
//   mods f32 [64][6][128]      192 KB
// mods slots per b: 0=alpha1(g1), 1=gamma1(be1), 2=beta1(al1),
//                   3=alpha2(g2), 4=gamma2(be2), 5=beta2(al2)   (bug-faithful)

#define NB 64

typedef __attribute__((ext_vector_type(8))) short bf16x8;
typedef __attribute__((ext_vector_type(4))) float f32x4;

__device__ __forceinline__ float silu_f(float x) { return x / (1.0f + __expf(-x)); }
__device__ __forceinline__ unsigned short f2bf(float x) {
    __hip_bfloat16 h = __float2bfloat16(x);
    return *reinterpret_cast<unsigned short*>(&h);
}

// ---------------- K1: cond MLPs ----------------
__global__ void __launch_bounds__(128) k_cond(
    const float* __restrict__ nodes, const float* __restrict__ tv,
    const float* __restrict__ w10, const float* __restrict__ b10,
    const float* __restrict__ w20, const float* __restrict__ b20,
    const float* __restrict__ w30, const float* __restrict__ b30,
    const float* __restrict__ w11, const float* __restrict__ b11,
    const float* __restrict__ w21, const float* __restrict__ b21,
    const float* __restrict__ w31, const float* __restrict__ b31,
    const float* __restrict__ w12, const float* __restrict__ b12,
    const float* __restrict__ w22, const float* __restrict__ b22,
    const float* __restrict__ w32, const float* __restrict__ b32,
    const float* __restrict__ w13, const float* __restrict__ b13,
    const float* __restrict__ w23, const float* __restrict__ b23,
    const float* __restrict__ w33, const float* __restrict__ b33,
    float* __restrict__ mods)
{
    int blk = blockIdx.x;
    int b = blk >> 2, m = blk & 3;
    const float* W1 = m==0?w10 : m==1?w11 : m==2?w12 : w13;
    const float* B1 = m==0?b10 : m==1?b11 : m==2?b12 : b13;
    const float* W2 = m==0?w20 : m==1?w21 : m==2?w22 : w23;
    const float* B2 = m==0?b20 : m==1?b21 : m==2?b22 : b23;
    const float* W3 = m==0?w30 : m==1?w31 : m==2?w32 : w33;
    const float* B3 = m==0?b30 : m==1?b31 : m==2?b32 : b33;
    int dout256 = (m == 0 || m == 2);
    int slot = (m==0)?0 : (m==1)?2 : (m==2)?3 : 5;

    __shared__ float xs[128], h1[128], h2[128];
    int t = threadIdx.x;
    xs[t] = nodes[b*128 + t] + tv[b];
    __syncthreads();

    float acc = B1[t];
    for (int i = 0; i < 128; i++) acc += xs[i] * W1[i*128 + t];
    h1[t] = silu_f(acc);
    __syncthreads();

    acc = B2[t];
    for (int i = 0; i < 128; i++) acc += h1[i] * W2[i*128 + t];
    h2[t] = silu_f(acc);
    __syncthreads();

    if (dout256) {
        float a0 = B3[t], a1 = B3[t + 128];
        for (int i = 0; i < 128; i++) {
            float h = h2[i];
            a0 += h * W3[i*256 + t];
            a1 += h * W3[i*256 + t + 128];
        }
        mods[((size_t)b*6 + slot    )*128 + t] = a0;
        mods[((size_t)b*6 + slot + 1)*128 + t] = a1;
    } else {
        float a0 = B3[t];
        for (int i = 0; i < 128; i++) a0 += h2[i] * W3[i*128 + t];
        mods[((size_t)b*6 + slot)*128 + t] = a0;
    }
}

// ---------------- K2: staticLN(ddof=1) + modulate + MFMA QKV -> bf16 ----------------
// grid = NB*8 blocks (b, 64-row tile), 256 threads (4 waves; wave = m-tile)
__global__ void __launch_bounds__(256, 1) k_norm_qkv(
    const float* __restrict__ latent, const float* __restrict__ mods,
    const float* __restrict__ qw, const float* __restrict__ kw, const float* __restrict__ vw,
    const float* __restrict__ qb, const float* __restrict__ kb, const float* __restrict__ vb,
    unsigned short* __restrict__ Qb, unsigned short* __restrict__ Kb,
    unsigned short* __restrict__ Vtb)
{
    __shared__ float xs[64*129];            // raw latent tile [n][d]
    __shared__ unsigned short xb[64*136];   // normalized bf16 [n][d] (reused as V staging [128][68])
    __shared__ unsigned short WtS[128*136]; // W^T bf16 [c][d]
    __shared__ float g1s[128], be1s[128], mean_s[64], rstd_s[64];

    int blk = blockIdx.x;
    int b = blk >> 3, n0 = (blk & 7) * 64;
    int t = threadIdx.x;

    if (t < 128) {
        g1s[t]  = mods[((size_t)b*6 + 1)*128 + t];  // gamma1 = be1 (bug)
        be1s[t] = mods[((size_t)b*6 + 2)*128 + t];  // beta1  = al1 (bug)
    }
    const float* lp = latent + (size_t)b*65536 + n0;
    for (int idx = t; idx < 8192; idx += 256) {
        int d = idx >> 6, j = idx & 63;
        xs[j*129 + d] = lp[(size_t)d*512 + j];
    }
    __syncthreads();

    {
        int row = t >> 2, sub = t & 3;
        float s = 0.f, ss = 0.f;
        const float* xr = &xs[row*129 + sub*32];
        #pragma unroll
        for (int i = 0; i < 32; i++) { float v = xr[i]; s += v; ss += v*v; }
        s += __shfl_xor(s, 1); ss += __shfl_xor(ss, 1);
        s += __shfl_xor(s, 2); ss += __shfl_xor(ss, 2);
        float mean = s * (1.0f/128.0f);
        float var = (ss - 128.0f*mean*mean) * (1.0f/127.0f);
        var = var < 0.f ? 0.f : var;
        float sd = sqrtf(var);
        mean_s[row] = mean;
        rstd_s[row] = (sd == 0.f) ? 1.f : 1.f/sd;
    }
    __syncthreads();

    for (int idx = t; idx < 8192; idx += 256) {
        int j = idx >> 7, d = idx & 127;
        float v = xs[j*129 + d];
        xb[j*136 + d] = f2bf(g1s[d]*((v - mean_s[j]) * rstd_s[j]) + be1s[d]);
    }
    __syncthreads();

    int w = t >> 6, lane = t & 63, lo = lane & 15, hi = lane >> 4;

    bf16x8 af[4];
    #pragma unroll
    for (int kc = 0; kc < 4; kc++)
        af[kc] = *(const bf16x8*)(xb + (w*16 + lo)*136 + kc*32 + hi*8);

    const f32x4 zero = {0.f, 0.f, 0.f, 0.f};
    // fold log2(e) into the 1/sqrt(dk) scale so k_attn can use exp2 directly
    const float qscale = 0.17677669529663687f * 1.4426950408889634f;

    #pragma unroll 1
    for (int ph = 0; ph < 3; ph++) {
        const float* wp = ph==0 ? qw : (ph==1 ? kw : vw);
        __syncthreads();
        for (int idx = t; idx < 16384; idx += 256) {
            int kk = idx & 31, d = (idx >> 5) & 127, h = idx >> 12;
            WtS[(h*32 + kk)*136 + d] = f2bf(wp[idx]);
        }
        __syncthreads();

        for (int nt = 0; nt < 8; nt++) {
            f32x4 acc = zero;
            #pragma unroll
            for (int kc = 0; kc < 4; kc++) {
                bf16x8 bf = *(const bf16x8*)(WtS + (nt*16 + lo)*136 + kc*32 + hi*8);
                acc = __builtin_amdgcn_mfma_f32_16x16x32_bf16(af[kc], bf, acc, 0, 0, 0);
            }
            int c = nt*16 + lo, h = c >> 5, kk = c & 31;
            size_t bh = (size_t)(b*4 + h);
            if (ph == 0) {
                float bias = qb[c];
                #pragma unroll
                for (int j = 0; j < 4; j++) {
                    int n = n0 + w*16 + hi*4 + j;
                    Qb[(bh*512 + n)*32 + kk] = f2bf((acc[j] + bias) * qscale);
                }
            } else if (ph == 1) {
                float bias = kb[c];
                #pragma unroll
                for (int j = 0; j < 4; j++) {
                    int n = n0 + w*16 + hi*4 + j;
                    Kb[(bh*512 + n)*32 + kk] = f2bf(acc[j] + bias);
                }
            } else {
                float bias = vb[c];
                #pragma unroll
                for (int j = 0; j < 4; j++) {
                    int nl = w*16 + hi*4 + j;
                    xb[c*68 + nl] = f2bf(acc[j] + bias);
                }
            }
        }
    }
    __syncthreads();
    for (int idx = t; idx < 8192; idx += 256) {
        int c = idx >> 6, j = idx & 63;
        int h = c >> 5, kk = c & 31;
        size_t bh = (size_t)(b*4 + h);
        Vtb[(bh*32 + kk)*512 + n0 + j] = xb[c*68 + j];
    }
}

// ---------------- K3: MFMA attention per (b,h), in-register P ----------------
// grid = NB*4 blocks, 512 threads (8 waves). Each wave: 64 q-rows (4 tiles).
// Swapped QK^T: s[kt] = mfma(K_frag, Q_frag) -> lane holds P[q=lo][keys kt*16+hi*4+j].
// PV: O^T = V^T x P^T; P^T B-frag assembled via 8 shfl + 4 selects per k-tile.
__global__ void __launch_bounds__(512, 2) k_attn(
    const unsigned short* __restrict__ Qb, const unsigned short* __restrict__ Kb,
    const unsigned short* __restrict__ Vtb, unsigned short* __restrict__ Ob)
{
    __shared__ unsigned short KsS[512*32];   // [key][dk] linear
    __shared__ unsigned short VsS[32*512];   // [dk][key], col ^= (row&7)<<3

    int bh = blockIdx.x;
    int t = threadIdx.x;

    const unsigned short* kgp = Kb + (size_t)bh*512*32;
    const unsigned short* vgp = Vtb + (size_t)bh*32*512;
    for (int idx = t; idx < 2048; idx += 512)
        *(bf16x8*)(KsS + idx*8) = *(const bf16x8*)(kgp + idx*8);
    for (int idx = t; idx < 2048; idx += 512) {
        int r = idx >> 6, cch = idx & 63;
        *(bf16x8*)(VsS + r*512 + ((cch*8) ^ ((r&7)<<3))) =
            *(const bf16x8*)(vgp + r*512 + cch*8);
    }
    __syncthreads();

    int w = t >> 6, lane = t & 63, lo = lane & 15, hi = lane >> 4;
    const unsigned short* qbase = Qb + (size_t)bh*512*32;
    const f32x4 zero = {0.f, 0.f, 0.f, 0.f};
    int b = bh >> 2, h = bh & 3;

    const unsigned short* Vl0 = VsS + lo*512;         // d = lo
    const unsigned short* Vl1 = VsS + (16 + lo)*512;  // d = 16+lo
    int swz = (lo & 7) << 3;
    int srcA = lo + 32*(hi & 1);

    for (int qt = 0; qt < 4; ++qt) {
        int q0 = w*64 + qt*16;
        bf16x8 qa = *(const bf16x8*)(qbase + (size_t)(q0 + lo)*32 + hi*8);

        // --- swapped QK^T: D[key][q], lane: q=lo, keys = kt*16 + hi*4 + j ---
        f32x4 s[32];
        #pragma unroll
        for (int kt = 0; kt < 32; ++kt) {
            bf16x8 kf = *(const bf16x8*)(KsS + (kt*16 + lo)*32 + hi*8);
            s[kt] = __builtin_amdgcn_mfma_f32_16x16x32_bf16(kf, qa, zero, 0, 0, 0);
        }

        // --- row max: in-lane (128 vals) + 2 shfl over the 4 hi-groups ---
        float m = -1e30f;
        #pragma unroll
        for (int kt = 0; kt < 32; ++kt)
            m = fmaxf(m, fmaxf(fmaxf(s[kt][0], s[kt][1]), fmaxf(s[kt][2], s[kt][3])));
        m = fmaxf(m, __shfl_xor(m, 16));
        m = fmaxf(m, __shfl_xor(m, 32));

        // --- p = exp2(s - m) (log2e pre-folded into Q), pack to bf16 pairs ---
        float sum = 0.f;
        unsigned int pw0[32], pw1[32];
        #pragma unroll
        for (int kt = 0; kt < 32; ++kt) {
            float p0 = __builtin_amdgcn_exp2f(s[kt][0] - m);
            float p1 = __builtin_amdgcn_exp2f(s[kt][1] - m);
            float p2 = __builtin_amdgcn_exp2f(s[kt][2] - m);
            float p3 = __builtin_amdgcn_exp2f(s[kt][3] - m);
            sum += (p0 + p1) + (p2 + p3);
            pw0[kt] = (unsigned)f2bf(p0) | ((unsigned)f2bf(p1) << 16);
            pw1[kt] = (unsigned)f2bf(p2) | ((unsigned)f2bf(p3) << 16);
        }
        sum += __shfl_xor(sum, 16);
        sum += __shfl_xor(sum, 32);

        // --- PV: O^T = V^T x P^T over 16 k-tiles of 32 keys ---
        // B-frag (lane lo,hi) needs P[q=lo][keys kt2*32 + hi*8 + 0..7]:
        //   words 0-1 from lane lo+32*(hi&1)      (E=kt 2kt2 if hi<2 else O=kt 2kt2+1)
        //   words 2-3 from lane lo+32*(hi&1)+16   (same E/O pick)
        f32x4 oa = zero, ob = zero;
        #pragma unroll
        for (int kt2 = 0; kt2 < 16; ++kt2) {
            unsigned e0 = pw0[2*kt2],     e1 = pw1[2*kt2];
            unsigned o0 = pw0[2*kt2 + 1], o1 = pw1[2*kt2 + 1];
            unsigned ae0 = (unsigned)__shfl((int)e0, srcA, 64);
            unsigned ae1 = (unsigned)__shfl((int)e1, srcA, 64);
            unsigned ao0 = (unsigned)__shfl((int)o0, srcA, 64);
            unsigned ao1 = (unsigned)__shfl((int)o1, srcA, 64);
            unsigned be0 = (unsigned)__shfl((int)e0, srcA + 16, 64);
            unsigned be1 = (unsigned)__shfl((int)e1, srcA + 16, 64);
            unsigned bo0 = (unsigned)__shfl((int)o0, srcA + 16, 64);
            unsigned bo1 = (unsigned)__shfl((int)o1, srcA + 16, 64);
            union { unsigned u[4]; bf16x8 v; } pb;
            pb.u[0] = (hi < 2) ? ae0 : ao0;
            pb.u[1] = (hi < 2) ? ae1 : ao1;
            pb.u[2] = (hi < 2) ? be0 : bo0;
            pb.u[3] = (hi < 2) ? be1 : bo1;
            int off = (kt2*32 + hi*8) ^ swz;
            bf16x8 v0 = *(const bf16x8*)(Vl0 + off);
            bf16x8 v1 = *(const bf16x8*)(Vl1 + off);
            oa = __builtin_amdgcn_mfma_f32_16x16x32_bf16(v0, pb.v, oa, 0, 0, 0);
            ob = __builtin_amdgcn_mfma_f32_16x16x32_bf16(v1, pb.v, ob, 0, 0, 0);
        }

        // --- store: lane holds O[q=q0+lo][d=hi*4+j (+16)]; i = d*4 + h ---
        float inv = 1.f / sum;
        unsigned short* op = Ob + ((size_t)(b*512 + q0 + lo))*128 + h;
        #pragma unroll
        for (int j = 0; j < 4; ++j) {
            op[(hi*4 + j)*4]       = f2bf(oa[j] * inv);
            op[(16 + hi*4 + j)*4]  = f2bf(ob[j] * inv);
        }
    }
}

// ---------------- K4: MFMA O@ow + residual + staticLN2 + residual + transpose-out ----
// grid = NB*8 blocks, 256 threads (4 waves; wave = m-tile)
__global__ void __launch_bounds__(256, 2) k_out(
    const float* __restrict__ latent, const unsigned short* __restrict__ Ob,
    const float* __restrict__ ow, const float* __restrict__ mods,
    float* __restrict__ outp)
{
    __shared__ unsigned short owT[128*136];  // ow^T bf16 [c][i]
    __shared__ float xs[64*129];
    __shared__ float a1s[128], a2s[128], g2s[128], b2s[128];
    __shared__ float mean_s[64], rstd_s[64];

    int blk = blockIdx.x;
    int b = blk >> 3, n0 = (blk & 7) * 64;
    int t = threadIdx.x;

    if (t < 128) {
        a1s[t] = mods[((size_t)b*6 + 0)*128 + t];  // alpha1 = g1 (bug)
        a2s[t] = mods[((size_t)b*6 + 3)*128 + t];  // alpha2 = g2 (bug)
        g2s[t] = mods[((size_t)b*6 + 4)*128 + t];  // gamma2 = be2 (bug)
        b2s[t] = mods[((size_t)b*6 + 5)*128 + t];  // beta2  = al2 (bug)
    }
    for (int idx = t; idx < 16384; idx += 256) {
        int i = idx >> 7, c = idx & 127;
        owT[c*136 + i] = f2bf(ow[idx]);
    }
    const float* lp = latent + (size_t)b*65536 + n0;
    for (int idx = t; idx < 8192; idx += 256) {
        int d = idx >> 6, j = idx & 63;
        xs[j*129 + d] = lp[(size_t)d*512 + j];
    }
    __syncthreads();

    int w = t >> 6, lane = t & 63, lo = lane & 15, hi = lane >> 4;

    const unsigned short* arow = Ob + ((size_t)(b*512 + n0 + w*16 + lo))*128;
    bf16x8 af[4];
    #pragma unroll
    for (int kc = 0; kc < 4; kc++)
        af[kc] = *(const bf16x8*)(arow + kc*32 + hi*8);

    const f32x4 zero = {0.f, 0.f, 0.f, 0.f};
    for (int nt = 0; nt < 8; nt++) {
        f32x4 acc = zero;
        #pragma unroll
        for (int kc = 0; kc < 4; kc++) {
            bf16x8 bf = *(const bf16x8*)(owT + (nt*16 + lo)*136 + kc*32 + hi*8);
            acc = __builtin_amdgcn_mfma_f32_16x16x32_bf16(af[kc], bf, acc, 0, 0, 0);
        }
        int c = nt*16 + lo;
        #pragma unroll
        for (int j = 0; j < 4; j++) {
            int nl = w*16 + hi*4 + j;
            xs[nl*129 + c] += a1s[c] * acc[j];
        }
    }
    __syncthreads();

    {
        int row = t >> 2, sub = t & 3;
        float s = 0.f, ss = 0.f;
        const float* xr = &xs[row*129 + sub*32];
        #pragma unroll
        for (int i = 0; i < 32; i++) { float v = xr[i]; s += v; ss += v*v; }
        s += __shfl_xor(s, 1); ss += __shfl_xor(ss, 1);
        s += __shfl_xor(s, 2); ss += __shfl_xor(ss, 2);
        float mean = s * (1.0f/128.0f);
        float var = (ss - 128.0f*mean*mean) * (1.0f/127.0f);
        var = var < 0.f ? 0.f : var;
        float sd = sqrtf(var);
        mean_s[row] = mean;
        rstd_s[row] = (sd == 0.f) ? 1.f : 1.f/sd;
    }
    __syncthreads();

    float* outb = outp + (size_t)b*65536 + n0;
    for (int idx = t; idx < 8192; idx += 256) {
        int d = idx >> 6, j = idx & 63;
        float v = xs[j*129 + d];
        float nv = (v - mean_s[j]) * rstd_s[j];
        outb[(size_t)d*512 + j] = v + a2s[d]*(g2s[d]*nv + b2s[d]);
    }
}

extern "C" void kernel_launch(void* const* d_in, const int* in_sizes, int n_in,
                              void* d_out, int out_size, void* d_ws, size_t ws_size,
                              hipStream_t stream) {
    const float* latent = (const float*)d_in[0];
    const float* nodes  = (const float*)d_in[1];
    const float* tv     = (const float*)d_in[2];
    const float* qw     = (const float*)d_in[3];
    const float* kw     = (const float*)d_in[4];
    const float* vw     = (const float*)d_in[5];
    const float* qb     = (const float*)d_in[6];
    const float* kb     = (const float*)d_in[7];
    const float* vb     = (const float*)d_in[8];
    const float* owp    = (const float*)d_in[9];

    const float* mw[24];
    for (int i = 0; i < 24; i++) mw[i] = (const float*)d_in[10 + i];

    char* wsb = (char*)d_ws;
    unsigned short* Qb  = (unsigned short*)(wsb);
    unsigned short* Kb  = (unsigned short*)(wsb + 8388608);
    unsigned short* Vtb = (unsigned short*)(wsb + 16777216);
    unsigned short* Ob  = (unsigned short*)(wsb + 25165824);
    float* mods = (float*)(wsb + 33554432);

    float* outp = (float*)d_out;

    k_cond<<<dim3(NB*4), dim3(128), 0, stream>>>(
        nodes, tv,
        mw[0], mw[1], mw[2], mw[3], mw[4], mw[5],
        mw[6], mw[7], mw[8], mw[9], mw[10], mw[11],
        mw[12], mw[13], mw[14], mw[15], mw[16], mw[17],
        mw[18], mw[19], mw[20], mw[21], mw[22], mw[23],
        mods);

    k_norm_qkv<<<dim3(NB*8), dim3(256), 0, stream>>>(
        latent, mods, qw, kw, vw, qb, kb, vb, Qb, Kb, Vtb);

    k_attn<<<dim3(NB*4), dim3(512), 0, stream>>>(Qb, Kb, Vtb, Ob);

    k_out<<<dim3(NB*8), dim3(256), 0, stream>>>(latent, Ob, owp, mods, outp);
}

// Round 8
// 224.957 us; speedup vs baseline: 1.2386x; 1.2386x over previous
//
#include <hip/hip_runtime.h>
#include <hip/hip_bf16.h>
#include <math.h>

// DiT block. b=64, n=512 (8x8x8), d=128, H=4, dk=32.
// Round 8: k_attn online-softmax chunked (kills round-7 register spills:
// 156MB scratch FETCH -> 0). Swapped QK^T, in-register P per 128-key chunk,
// grid 512 (2 q-halves/bh) for 2-blocks/CU occupancy.
// ws layout (bytes):
//   Qb  bf16 [64][4][512][32]   8 MB  (pre-scaled by log2e/sqrt(32))
//   Kb  bf16 [64][4][512][32]   8 MB
//   Vtb bf16 [64][4][32][512]   8 MB  (transposed [dk][n])
//   Ob  bf16 [64][512][128]     8 MB  (i-ordered: i = k*4+h, permute pre-applied)
//   mods f32 [64][6][128]      192 KB
// mods slots per b: 0=alpha1(g1), 1=gamma1(be1), 2=beta1(al1),
//                   3=alpha2(g2), 4=gamma2(be2), 5=beta2(al2)   (bug-faithful)

#define NB 64

typedef __attribute__((ext_vector_type(8))) short bf16x8;
typedef __attribute__((ext_vector_type(4))) float f32x4;

__device__ __forceinline__ float silu_f(float x) { return x / (1.0f + __expf(-x)); }
__device__ __forceinline__ unsigned short f2bf(float x) {
    __hip_bfloat16 h = __float2bfloat16(x);
    return *reinterpret_cast<unsigned short*>(&h);
}

// ---------------- K1: cond MLPs ----------------
__global__ void __launch_bounds__(128) k_cond(
    const float* __restrict__ nodes, const float* __restrict__ tv,
    const float* __restrict__ w10, const float* __restrict__ b10,
    const float* __restrict__ w20, const float* __restrict__ b20,
    const float* __restrict__ w30, const float* __restrict__ b30,
    const float* __restrict__ w11, const float* __restrict__ b11,
    const float* __restrict__ w21, const float* __restrict__ b21,
    const float* __restrict__ w31, const float* __restrict__ b31,
    const float* __restrict__ w12, const float* __restrict__ b12,
    const float* __restrict__ w22, const float* __restrict__ b22,
    const float* __restrict__ w32, const float* __restrict__ b32,
    const float* __restrict__ w13, const float* __restrict__ b13,
    const float* __restrict__ w23, const float* __restrict__ b23,
    const float* __restrict__ w33, const float* __restrict__ b33,
    float* __restrict__ mods)
{
    int blk = blockIdx.x;
    int b = blk >> 2, m = blk & 3;
    const float* W1 = m==0?w10 : m==1?w11 : m==2?w12 : w13;
    const float* B1 = m==0?b10 : m==1?b11 : m==2?b12 : b13;
    const float* W2 = m==0?w20 : m==1?w21 : m==2?w22 : w23;
    const float* B2 = m==0?b20 : m==1?b21 : m==2?b22 : b23;
    const float* W3 = m==0?w30 : m==1?w31 : m==2?w32 : w33;
    const float* B3 = m==0?b30 : m==1?b31 : m==2?b32 : b33;
    int dout256 = (m == 0 || m == 2);
    int slot = (m==0)?0 : (m==1)?2 : (m==2)?3 : 5;

    __shared__ float xs[128], h1[128], h2[128];
    int t = threadIdx.x;
    xs[t] = nodes[b*128 + t] + tv[b];
    __syncthreads();

    float acc = B1[t];
    for (int i = 0; i < 128; i++) acc += xs[i] * W1[i*128 + t];
    h1[t] = silu_f(acc);
    __syncthreads();

    acc = B2[t];
    for (int i = 0; i < 128; i++) acc += h1[i] * W2[i*128 + t];
    h2[t] = silu_f(acc);
    __syncthreads();

    if (dout256) {
        float a0 = B3[t], a1 = B3[t + 128];
        for (int i = 0; i < 128; i++) {
            float h = h2[i];
            a0 += h * W3[i*256 + t];
            a1 += h * W3[i*256 + t + 128];
        }
        mods[((size_t)b*6 + slot    )*128 + t] = a0;
        mods[((size_t)b*6 + slot + 1)*128 + t] = a1;
    } else {
        float a0 = B3[t];
        for (int i = 0; i < 128; i++) a0 += h2[i] * W3[i*128 + t];
        mods[((size_t)b*6 + slot)*128 + t] = a0;
    }
}

// ---------------- K2: staticLN(ddof=1) + modulate + MFMA QKV -> bf16 ----------------
// grid = NB*8 blocks (b, 64-row tile), 256 threads (4 waves; wave = m-tile)
__global__ void __launch_bounds__(256, 1) k_norm_qkv(
    const float* __restrict__ latent, const float* __restrict__ mods,
    const float* __restrict__ qw, const float* __restrict__ kw, const float* __restrict__ vw,
    const float* __restrict__ qb, const float* __restrict__ kb, const float* __restrict__ vb,
    unsigned short* __restrict__ Qb, unsigned short* __restrict__ Kb,
    unsigned short* __restrict__ Vtb)
{
    __shared__ float xs[64*129];            // raw latent tile [n][d]
    __shared__ unsigned short xb[64*136];   // normalized bf16 [n][d] (reused as V staging [128][68])
    __shared__ unsigned short WtS[128*136]; // W^T bf16 [c][d]
    __shared__ float g1s[128], be1s[128], mean_s[64], rstd_s[64];

    int blk = blockIdx.x;
    int b = blk >> 3, n0 = (blk & 7) * 64;
    int t = threadIdx.x;

    if (t < 128) {
        g1s[t]  = mods[((size_t)b*6 + 1)*128 + t];  // gamma1 = be1 (bug)
        be1s[t] = mods[((size_t)b*6 + 2)*128 + t];  // beta1  = al1 (bug)
    }
    const float* lp = latent + (size_t)b*65536 + n0;
    for (int idx = t; idx < 8192; idx += 256) {
        int d = idx >> 6, j = idx & 63;
        xs[j*129 + d] = lp[(size_t)d*512 + j];
    }
    __syncthreads();

    {
        int row = t >> 2, sub = t & 3;
        float s = 0.f, ss = 0.f;
        const float* xr = &xs[row*129 + sub*32];
        #pragma unroll
        for (int i = 0; i < 32; i++) { float v = xr[i]; s += v; ss += v*v; }
        s += __shfl_xor(s, 1); ss += __shfl_xor(ss, 1);
        s += __shfl_xor(s, 2); ss += __shfl_xor(ss, 2);
        float mean = s * (1.0f/128.0f);
        float var = (ss - 128.0f*mean*mean) * (1.0f/127.0f);
        var = var < 0.f ? 0.f : var;
        float sd = sqrtf(var);
        mean_s[row] = mean;
        rstd_s[row] = (sd == 0.f) ? 1.f : 1.f/sd;
    }
    __syncthreads();

    for (int idx = t; idx < 8192; idx += 256) {
        int j = idx >> 7, d = idx & 127;
        float v = xs[j*129 + d];
        xb[j*136 + d] = f2bf(g1s[d]*((v - mean_s[j]) * rstd_s[j]) + be1s[d]);
    }
    __syncthreads();

    int w = t >> 6, lane = t & 63, lo = lane & 15, hi = lane >> 4;

    bf16x8 af[4];
    #pragma unroll
    for (int kc = 0; kc < 4; kc++)
        af[kc] = *(const bf16x8*)(xb + (w*16 + lo)*136 + kc*32 + hi*8);

    const f32x4 zero = {0.f, 0.f, 0.f, 0.f};
    // fold log2(e) into the 1/sqrt(dk) scale so k_attn can use exp2 directly
    const float qscale = 0.17677669529663687f * 1.4426950408889634f;

    #pragma unroll 1
    for (int ph = 0; ph < 3; ph++) {
        const float* wp = ph==0 ? qw : (ph==1 ? kw : vw);
        __syncthreads();
        for (int idx = t; idx < 16384; idx += 256) {
            int kk = idx & 31, d = (idx >> 5) & 127, h = idx >> 12;
            WtS[(h*32 + kk)*136 + d] = f2bf(wp[idx]);
        }
        __syncthreads();

        for (int nt = 0; nt < 8; nt++) {
            f32x4 acc = zero;
            #pragma unroll
            for (int kc = 0; kc < 4; kc++) {
                bf16x8 bf = *(const bf16x8*)(WtS + (nt*16 + lo)*136 + kc*32 + hi*8);
                acc = __builtin_amdgcn_mfma_f32_16x16x32_bf16(af[kc], bf, acc, 0, 0, 0);
            }
            int c = nt*16 + lo, h = c >> 5, kk = c & 31;
            size_t bh = (size_t)(b*4 + h);
            if (ph == 0) {
                float bias = qb[c];
                #pragma unroll
                for (int j = 0; j < 4; j++) {
                    int n = n0 + w*16 + hi*4 + j;
                    Qb[(bh*512 + n)*32 + kk] = f2bf((acc[j] + bias) * qscale);
                }
            } else if (ph == 1) {
                float bias = kb[c];
                #pragma unroll
                for (int j = 0; j < 4; j++) {
                    int n = n0 + w*16 + hi*4 + j;
                    Kb[(bh*512 + n)*32 + kk] = f2bf(acc[j] + bias);
                }
            } else {
                float bias = vb[c];
                #pragma unroll
                for (int j = 0; j < 4; j++) {
                    int nl = w*16 + hi*4 + j;
                    xb[c*68 + nl] = f2bf(acc[j] + bias);
                }
            }
        }
    }
    __syncthreads();
    for (int idx = t; idx < 8192; idx += 256) {
        int c = idx >> 6, j = idx & 63;
        int h = c >> 5, kk = c & 31;
        size_t bh = (size_t)(b*4 + h);
        Vtb[(bh*32 + kk)*512 + n0 + j] = xb[c*68 + j];
    }
}

// ---------------- K3: MFMA attention, online-softmax chunked ----------------
// grid = NB*4*2 blocks (bh, q-half), 512 threads (8 waves).
// Each wave: 32 q-rows (2 tiles of 16). Keys processed in 4 chunks of 128:
// only s8[8] + packed P live per chunk -> no VGPR spill.
__global__ void __launch_bounds__(512, 4) k_attn(
    const unsigned short* __restrict__ Qb, const unsigned short* __restrict__ Kb,
    const unsigned short* __restrict__ Vtb, unsigned short* __restrict__ Ob)
{
    __shared__ unsigned short KsS[512*32];   // [key][dk] linear
    __shared__ unsigned short VsS[32*512];   // [dk][key], col ^= (row&7)<<3

    int blk = blockIdx.x;
    int bh = blk >> 1, qhalf = blk & 1;
    int t = threadIdx.x;

    const unsigned short* kgp = Kb + (size_t)bh*512*32;
    const unsigned short* vgp = Vtb + (size_t)bh*32*512;
    for (int idx = t; idx < 2048; idx += 512)
        *(bf16x8*)(KsS + idx*8) = *(const bf16x8*)(kgp + idx*8);
    for (int idx = t; idx < 2048; idx += 512) {
        int r = idx >> 6, cch = idx & 63;
        *(bf16x8*)(VsS + r*512 + ((cch*8) ^ ((r&7)<<3))) =
            *(const bf16x8*)(vgp + r*512 + cch*8);
    }
    __syncthreads();

    int w = t >> 6, lane = t & 63, lo = lane & 15, hi = lane >> 4;
    const unsigned short* qbase = Qb + (size_t)bh*512*32;
    const f32x4 zero = {0.f, 0.f, 0.f, 0.f};
    int b = bh >> 2, h = bh & 3;

    const unsigned short* Vl0 = VsS + lo*512;         // d = lo
    const unsigned short* Vl1 = VsS + (16 + lo)*512;  // d = 16+lo
    int swz = (lo & 7) << 3;
    int srcA = lo + 32*(hi & 1);

    for (int qt = 0; qt < 2; ++qt) {
        int q0 = qhalf*256 + w*32 + qt*16;
        bf16x8 qa = *(const bf16x8*)(qbase + (size_t)(q0 + lo)*32 + hi*8);

        float m = -1e30f, sum = 0.f;
        f32x4 oa = zero, ob = zero;

        #pragma unroll 1
        for (int ch = 0; ch < 4; ++ch) {
            // --- swapped QK^T for this 128-key chunk ---
            f32x4 s8[8];
            #pragma unroll
            for (int kt = 0; kt < 8; ++kt) {
                bf16x8 kf = *(const bf16x8*)(KsS + ((ch*8 + kt)*16 + lo)*32 + hi*8);
                s8[kt] = __builtin_amdgcn_mfma_f32_16x16x32_bf16(kf, qa, zero, 0, 0, 0);
            }

            // --- chunk max (row q=lo), uniform across hi-groups ---
            float cm = -1e30f;
            #pragma unroll
            for (int kt = 0; kt < 8; ++kt)
                cm = fmaxf(cm, fmaxf(fmaxf(s8[kt][0], s8[kt][1]), fmaxf(s8[kt][2], s8[kt][3])));
            cm = fmaxf(cm, __shfl_xor(cm, 16));
            cm = fmaxf(cm, __shfl_xor(cm, 32));
            float nm = fmaxf(m, cm);
            float sc = __builtin_amdgcn_exp2f(m - nm);
            sum *= sc;
            #pragma unroll
            for (int j = 0; j < 4; ++j) { oa[j] *= sc; ob[j] *= sc; }
            m = nm;

            // --- p = exp2(s - m), pack to bf16 pairs ---
            unsigned pw0c[8], pw1c[8];
            #pragma unroll
            for (int kt = 0; kt < 8; ++kt) {
                float p0 = __builtin_amdgcn_exp2f(s8[kt][0] - nm);
                float p1 = __builtin_amdgcn_exp2f(s8[kt][1] - nm);
                float p2 = __builtin_amdgcn_exp2f(s8[kt][2] - nm);
                float p3 = __builtin_amdgcn_exp2f(s8[kt][3] - nm);
                sum += (p0 + p1) + (p2 + p3);
                pw0c[kt] = (unsigned)f2bf(p0) | ((unsigned)f2bf(p1) << 16);
                pw1c[kt] = (unsigned)f2bf(p2) | ((unsigned)f2bf(p3) << 16);
            }

            // --- PV for this chunk: 4 k-tiles of 32 keys ---
            #pragma unroll
            for (int kt2 = 0; kt2 < 4; ++kt2) {
                unsigned e0 = pw0c[2*kt2],     e1 = pw1c[2*kt2];
                unsigned o0 = pw0c[2*kt2 + 1], o1 = pw1c[2*kt2 + 1];
                unsigned ae0 = (unsigned)__shfl((int)e0, srcA, 64);
                unsigned ae1 = (unsigned)__shfl((int)e1, srcA, 64);
                unsigned ao0 = (unsigned)__shfl((int)o0, srcA, 64);
                unsigned ao1 = (unsigned)__shfl((int)o1, srcA, 64);
                unsigned be0 = (unsigned)__shfl((int)e0, srcA + 16, 64);
                unsigned be1 = (unsigned)__shfl((int)e1, srcA + 16, 64);
                unsigned bo0 = (unsigned)__shfl((int)o0, srcA + 16, 64);
                unsigned bo1 = (unsigned)__shfl((int)o1, srcA + 16, 64);
                union { unsigned u[4]; bf16x8 v; } pb;
                pb.u[0] = (hi < 2) ? ae0 : ao0;
                pb.u[1] = (hi < 2) ? ae1 : ao1;
                pb.u[2] = (hi < 2) ? be0 : bo0;
                pb.u[3] = (hi < 2) ? be1 : bo1;
                int off = (((ch*4 + kt2)*32) + hi*8) ^ swz;
                bf16x8 v0 = *(const bf16x8*)(Vl0 + off);
                bf16x8 v1 = *(const bf16x8*)(Vl1 + off);
                oa = __builtin_amdgcn_mfma_f32_16x16x32_bf16(v0, pb.v, oa, 0, 0, 0);
                ob = __builtin_amdgcn_mfma_f32_16x16x32_bf16(v1, pb.v, ob, 0, 0, 0);
            }
        }

        sum += __shfl_xor(sum, 16);
        sum += __shfl_xor(sum, 32);

        // --- store: lane holds O[q=q0+lo][d=hi*4+j (+16)]; i = d*4 + h ---
        float inv = 1.f / sum;
        unsigned short* op = Ob + ((size_t)(b*512 + q0 + lo))*128 + h;
        #pragma unroll
        for (int j = 0; j < 4; ++j) {
            op[(hi*4 + j)*4]       = f2bf(oa[j] * inv);
            op[(16 + hi*4 + j)*4]  = f2bf(ob[j] * inv);
        }
    }
}

// ---------------- K4: MFMA O@ow + residual + staticLN2 + residual + transpose-out ----
// grid = NB*8 blocks, 256 threads (4 waves; wave = m-tile)
__global__ void __launch_bounds__(256, 2) k_out(
    const float* __restrict__ latent, const unsigned short* __restrict__ Ob,
    const float* __restrict__ ow, const float* __restrict__ mods,
    float* __restrict__ outp)
{
    __shared__ unsigned short owT[128*136];  // ow^T bf16 [c][i]
    __shared__ float xs[64*129];
    __shared__ float a1s[128], a2s[128], g2s[128], b2s[128];
    __shared__ float mean_s[64], rstd_s[64];

    int blk = blockIdx.x;
    int b = blk >> 3, n0 = (blk & 7) * 64;
    int t = threadIdx.x;

    if (t < 128) {
        a1s[t] = mods[((size_t)b*6 + 0)*128 + t];  // alpha1 = g1 (bug)
        a2s[t] = mods[((size_t)b*6 + 3)*128 + t];  // alpha2 = g2 (bug)
        g2s[t] = mods[((size_t)b*6 + 4)*128 + t];  // gamma2 = be2 (bug)
        b2s[t] = mods[((size_t)b*6 + 5)*128 + t];  // beta2  = al2 (bug)
    }
    for (int idx = t; idx < 16384; idx += 256) {
        int i = idx >> 7, c = idx & 127;
        owT[c*136 + i] = f2bf(ow[idx]);
    }
    const float* lp = latent + (size_t)b*65536 + n0;
    for (int idx = t; idx < 8192; idx += 256) {
        int d = idx >> 6, j = idx & 63;
        xs[j*129 + d] = lp[(size_t)d*512 + j];
    }
    __syncthreads();

    int w = t >> 6, lane = t & 63, lo = lane & 15, hi = lane >> 4;

    const unsigned short* arow = Ob + ((size_t)(b*512 + n0 + w*16 + lo))*128;
    bf16x8 af[4];
    #pragma unroll
    for (int kc = 0; kc < 4; kc++)
        af[kc] = *(const bf16x8*)(arow + kc*32 + hi*8);

    const f32x4 zero = {0.f, 0.f, 0.f, 0.f};
    for (int nt = 0; nt < 8; nt++) {
        f32x4 acc = zero;
        #pragma unroll
        for (int kc = 0; kc < 4; kc++) {
            bf16x8 bf = *(const bf16x8*)(owT + (nt*16 + lo)*136 + kc*32 + hi*8);
            acc = __builtin_amdgcn_mfma_f32_16x16x32_bf16(af[kc], bf, acc, 0, 0, 0);
        }
        int c = nt*16 + lo;
        #pragma unroll
        for (int j = 0; j < 4; j++) {
            int nl = w*16 + hi*4 + j;
            xs[nl*129 + c] += a1s[c] * acc[j];
        }
    }
    __syncthreads();

    {
        int row = t >> 2, sub = t & 3;
        float s = 0.f, ss = 0.f;
        const float* xr = &xs[row*129 + sub*32];
        #pragma unroll
        for (int i = 0; i < 32; i++) { float v = xr[i]; s += v; ss += v*v; }
        s += __shfl_xor(s, 1); ss += __shfl_xor(ss, 1);
        s += __shfl_xor(s, 2); ss += __shfl_xor(ss, 2);
        float mean = s * (1.0f/128.0f);
        float var = (ss - 128.0f*mean*mean) * (1.0f/127.0f);
        var = var < 0.f ? 0.f : var;
        float sd = sqrtf(var);
        mean_s[row] = mean;
        rstd_s[row] = (sd == 0.f) ? 1.f : 1.f/sd;
    }
    __syncthreads();

    float* outb = outp + (size_t)b*65536 + n0;
    for (int idx = t; idx < 8192; idx += 256) {
        int d = idx >> 6, j = idx & 63;
        float v = xs[j*129 + d];
        float nv = (v - mean_s[j]) * rstd_s[j];
        outb[(size_t)d*512 + j] = v + a2s[d]*(g2s[d]*nv + b2s[d]);
    }
}

extern "C" void kernel_launch(void* const* d_in, const int* in_sizes, int n_in,
                              void* d_out, int out_size, void* d_ws, size_t ws_size,
                              hipStream_t stream) {
    const float* latent = (const float*)d_in[0];
    const float* nodes  = (const float*)d_in[1];
    const float* tv     = (const float*)d_in[2];
    const float* qw     = (const float*)d_in[3];
    const float* kw     = (const float*)d_in[4];
    const float* vw     = (const float*)d_in[5];
    const float* qb     = (const float*)d_in[6];
    const float* kb     = (const float*)d_in[7];
    const float* vb     = (const float*)d_in[8];
    const float* owp    = (const float*)d_in[9];

    const float* mw[24];
    for (int i = 0; i < 24; i++) mw[i] = (const float*)d_in[10 + i];

    char* wsb = (char*)d_ws;
    unsigned short* Qb  = (unsigned short*)(wsb);
    unsigned short* Kb  = (unsigned short*)(wsb + 8388608);
    unsigned short* Vtb = (unsigned short*)(wsb + 16777216);
    unsigned short* Ob  = (unsigned short*)(wsb + 25165824);
    float* mods = (float*)(wsb + 33554432);

    float* outp = (float*)d_out;

    k_cond<<<dim3(NB*4), dim3(128), 0, stream>>>(
        nodes, tv,
        mw[0], mw[1], mw[2], mw[3], mw[4], mw[5],
        mw[6], mw[7], mw[8], mw[9], mw[10], mw[11],
        mw[12], mw[13], mw[14], mw[15], mw[16], mw[17],
        mw[18], mw[19], mw[20], mw[21], mw[22], mw[23],
        mods);

    k_norm_qkv<<<dim3(NB*8), dim3(256), 0, stream>>>(
        latent, mods, qw, kw, vw, qb, kb, vb, Qb, Kb, Vtb);

    k_attn<<<dim3(NB*4*2), dim3(512), 0, stream>>>(Qb, Kb, Vtb, Ob);

    k_out<<<dim3(NB*8), dim3(256), 0, stream>>>(latent, Ob, owp, mods, outp);
}